// Round 1
// baseline (136.262 us; speedup 1.0000x reference)
//
#include <hip/hip_runtime.h>
#include <math.h>

#define BATCH 64
#define H 512
#define W 512
#define KRAD 15
#define RCHUNK 64
#define NRC (H / RCHUNK)            // 8 row chunks
#define NCG (W / 256)               // 2 column groups
#define BLOCKS_PER_IMG (NRC * NCG)  // 16

__device__ __forceinline__ float wave_reduce(float v) {
    #pragma unroll
    for (int off = 32; off > 0; off >>= 1) v += __shfl_xor(v, off);
    return v;
}

// -------- Pass 1: horizontal 31-wide box sum (zero padded), one wave per row.
__global__ __launch_bounds__(256) void hbox_kernel(const float* __restrict__ mask,
                                                   float* __restrict__ hsum) {
    const int wave = threadIdx.x >> 6;
    const int lane = threadIdx.x & 63;
    const int row  = blockIdx.x * 4 + wave;          // [0, BATCH*H)
    const float* in  = mask + (size_t)row * W;
    float*       out = hsum + (size_t)row * W;

    // lane owns 8 consecutive elements x = 8*lane + k
    const float4* in4 = reinterpret_cast<const float4*>(in + lane * 8);
    float4 va = in4[0], vb = in4[1];
    float v[8] = {va.x, va.y, va.z, va.w, vb.x, vb.y, vb.z, vb.w};

    // per-lane inclusive prefix
    float P[8];
    float run = 0.f;
    #pragma unroll
    for (int k = 0; k < 8; ++k) { run += v[k]; P[k] = run; }
    const float tot = run;

    // wave inclusive scan of lane totals
    float scan = tot;
    #pragma unroll
    for (int off = 1; off < 64; off <<= 1) {
        float n = __shfl_up(scan, off);
        if (lane >= off) scan += n;
    }
    const float excl = scan - tot;
    #pragma unroll
    for (int k = 0; k < 8; ++k) P[k] += excl;     // P[k] = inclusive prefix at x=8*lane+k
    const float total = __shfl(P[7], 63);         // prefix at x=511

    // out[x] = P[min(x+15,511)] - (x>=16 ? P[x-16] : 0)
    // x+15 = 8*lane+k+15 -> k==0: lane+1 reg7 ; k>=1: lane+2 reg k-1
    // x-16 = 8*(lane-2)+k -> lane-2 reg k
    float shA[8], shB[8];
    shA[0] = __shfl_down(P[7], 1);
    #pragma unroll
    for (int k = 1; k < 8; ++k) shA[k] = __shfl_down(P[k - 1], 2);
    #pragma unroll
    for (int k = 0; k < 8; ++k) shB[k] = __shfl_up(P[k], 2);

    const int xbase = lane * 8;
    float o[8];
    #pragma unroll
    for (int k = 0; k < 8; ++k) {
        const int x = xbase + k;
        const float A  = (x + KRAD <= W - 1) ? shA[k] : total;
        const float Bv = (x >= KRAD + 1) ? shB[k] : 0.0f;
        o[k] = A - Bv;
    }
    float4* out4 = reinterpret_cast<float4*>(out + xbase);
    out4[0] = make_float4(o[0], o[1], o[2], o[3]);
    out4[1] = make_float4(o[4], o[5], o[6], o[7]);
}

// -------- Pass 2: vertical running 31-sum + fused weight/BCE/IoU, partials per block.
__global__ __launch_bounds__(256) void loss_kernel(const float* __restrict__ pred,
                                                   const float* __restrict__ mask,
                                                   const float* __restrict__ hsum,
                                                   float2* __restrict__ partials) {
    const int tid = threadIdx.x;
    const int img = blockIdx.x / BLOCKS_PER_IMG;
    const int rem = blockIdx.x % BLOCKS_PER_IMG;
    const int cg  = rem & (NCG - 1);
    const int rc  = rem / NCG;
    const int col = cg * 256 + tid;
    const int r0  = rc * RCHUNK;
    const size_t base = (size_t)img * H * W;
    const float* hs = hsum + base;
    const float* mk = mask + base;
    const float* pr = pred + base;
    const float inv_k2 = 1.0f / 961.0f;

    // warm-up window sum over rows [r0-15, r0+15]
    float vsum = 0.f;
    #pragma unroll
    for (int dy = -KRAD; dy <= KRAD; ++dy) {
        const int y = r0 + dy;
        if (y >= 0 && y < H) vsum += hs[y * W + col];
    }

    float s0 = 0.f, s1 = 0.f;
    for (int y = r0; y < r0 + RCHUNK; ++y) {
        const float avg = vsum * inv_k2;
        const float m = mk[y * W + col];
        const float p = pr[y * W + col];
        const float w = 1.0f + 5.0f * fabsf(avg - m);
        const float bce = fmaxf(p, 0.0f) - p * m + log1pf(expf(-fabsf(p)));
        const float sig = 1.0f / (1.0f + expf(-p));
        const float inter = sig * m;
        const float denom = sig + m - inter + 1.0f;   // union - inter + 1
        const float iou = 1.0f - (inter + 1.0f) / denom;
        s0 += w;
        s1 += w * (bce + iou);
        // slide window: add y+16, drop y-15
        const int ya = y + KRAD + 1;
        if (ya < H) vsum += hs[ya * W + col];
        const int yr = y - KRAD;
        if (yr >= 0) vsum -= hs[yr * W + col];
    }

    s0 = wave_reduce(s0);
    s1 = wave_reduce(s1);
    __shared__ float2 wacc[4];
    const int lane = tid & 63, wv = tid >> 6;
    if (lane == 0) wacc[wv] = make_float2(s0, s1);
    __syncthreads();
    if (tid == 0) {
        float a0 = 0.f, a1 = 0.f;
        #pragma unroll
        for (int i = 0; i < 4; ++i) { a0 += wacc[i].x; a1 += wacc[i].y; }
        partials[blockIdx.x] = make_float2(a0, a1);
    }
}

// -------- Pass 3: per-image ratio, mean over 64 images. One wave.
__global__ void finalize_kernel(const float2* __restrict__ partials,
                                float* __restrict__ out) {
    const int lane = threadIdx.x;   // 64 threads, one per image
    float s0 = 0.f, s1 = 0.f;
    #pragma unroll
    for (int j = 0; j < BLOCKS_PER_IMG; ++j) {
        const float2 pp = partials[lane * BLOCKS_PER_IMG + j];
        s0 += pp.x; s1 += pp.y;
    }
    float q = s1 / s0;
    q = wave_reduce(q);
    if (lane == 0) out[0] = q * (1.0f / (float)BATCH);
}

extern "C" void kernel_launch(void* const* d_in, const int* in_sizes, int n_in,
                              void* d_out, int out_size, void* d_ws, size_t ws_size,
                              hipStream_t stream) {
    const float* pred = (const float*)d_in[0];
    const float* mask = (const float*)d_in[1];
    float* hsum = (float*)d_ws;
    float2* partials = (float2*)((char*)d_ws + (size_t)BATCH * H * W * sizeof(float));

    hipLaunchKernelGGL(hbox_kernel, dim3(BATCH * H / 4), dim3(256), 0, stream,
                       mask, hsum);
    hipLaunchKernelGGL(loss_kernel, dim3(BATCH * BLOCKS_PER_IMG), dim3(256), 0, stream,
                       pred, mask, hsum, partials);
    hipLaunchKernelGGL(finalize_kernel, dim3(1), dim3(64), 0, stream,
                       partials, (float*)d_out);
}

// Round 2
// 77.728 us; speedup vs baseline: 1.7531x; 1.7531x over previous
//
#include <hip/hip_runtime.h>
#include <math.h>

#define BATCH 64
#define H 512
#define W 512
#define KRAD 15
#define RCHUNK 32
#define NRC (H / RCHUNK)            // 16 row chunks
#define NCG (W / 256)               // 2 column groups
#define BLOCKS_PER_IMG (NRC * NCG)  // 32

__device__ __forceinline__ float wave_reduce(float v) {
    #pragma unroll
    for (int off = 32; off > 0; off >>= 1) v += __shfl_xor(v, off);
    return v;
}

// -------- Pass 1: horizontal 31-wide box sum (zero padded), one wave per row.
__global__ __launch_bounds__(256) void hbox_kernel(const float* __restrict__ mask,
                                                   float* __restrict__ hsum) {
    const int wave = threadIdx.x >> 6;
    const int lane = threadIdx.x & 63;
    const int row  = blockIdx.x * 4 + wave;          // [0, BATCH*H)
    const float* in  = mask + (size_t)row * W;
    float*       out = hsum + (size_t)row * W;

    // lane owns 8 consecutive elements x = 8*lane + k
    const float4* in4 = reinterpret_cast<const float4*>(in + lane * 8);
    float4 va = in4[0], vb = in4[1];
    float v[8] = {va.x, va.y, va.z, va.w, vb.x, vb.y, vb.z, vb.w};

    // per-lane inclusive prefix
    float P[8];
    float run = 0.f;
    #pragma unroll
    for (int k = 0; k < 8; ++k) { run += v[k]; P[k] = run; }
    const float tot = run;

    // wave inclusive scan of lane totals
    float scan = tot;
    #pragma unroll
    for (int off = 1; off < 64; off <<= 1) {
        float n = __shfl_up(scan, off);
        if (lane >= off) scan += n;
    }
    const float excl = scan - tot;
    #pragma unroll
    for (int k = 0; k < 8; ++k) P[k] += excl;     // inclusive prefix at x=8*lane+k
    const float total = __shfl(P[7], 63);         // prefix at x=511

    // out[x] = P[min(x+15,511)] - (x>=16 ? P[x-16] : 0)
    float shA[8], shB[8];
    shA[0] = __shfl_down(P[7], 1);
    #pragma unroll
    for (int k = 1; k < 8; ++k) shA[k] = __shfl_down(P[k - 1], 2);
    #pragma unroll
    for (int k = 0; k < 8; ++k) shB[k] = __shfl_up(P[k], 2);

    const int xbase = lane * 8;
    float o[8];
    #pragma unroll
    for (int k = 0; k < 8; ++k) {
        const int x = xbase + k;
        const float A  = (x + KRAD <= W - 1) ? shA[k] : total;
        const float Bv = (x >= KRAD + 1) ? shB[k] : 0.0f;
        o[k] = A - Bv;
    }
    float4* out4 = reinterpret_cast<float4*>(out + xbase);
    out4[0] = make_float4(o[0], o[1], o[2], o[3]);
    out4[1] = make_float4(o[4], o[5], o[6], o[7]);
}

// -------- Pass 2: vertical running 31-sum + fused weight/BCE/IoU, partials per block.
__global__ __launch_bounds__(256) void loss_kernel(const float* __restrict__ pred,
                                                   const float* __restrict__ mask,
                                                   const float* __restrict__ hsum,
                                                   float2* __restrict__ partials) {
    const int tid = threadIdx.x;
    const int img = blockIdx.x / BLOCKS_PER_IMG;
    const int rem = blockIdx.x % BLOCKS_PER_IMG;
    const int cg  = rem & (NCG - 1);
    const int rc  = rem / NCG;
    const int col = cg * 256 + tid;
    const int r0  = rc * RCHUNK;
    const size_t base = (size_t)img * H * W;
    const float* hs = hsum + base + col;
    const float* mk = mask + base + col;
    const float* pr = pred + base + col;
    const float inv_k2 = 1.0f / 961.0f;

    // warm-up window sum over rows [r0-15, r0+15]
    float vsum = 0.f;
    #pragma unroll
    for (int dy = -KRAD; dy <= KRAD; ++dy) {
        const int y = r0 + dy;
        if (y >= 0 && y < H) vsum += hs[y * W];
    }

    float s0 = 0.f, s1 = 0.f;
    #pragma unroll 4
    for (int y = r0; y < r0 + RCHUNK; ++y) {
        const float avg = vsum * inv_k2;
        const float m = mk[y * W];
        const float p = pr[y * W];
        const float w = 1.0f + 5.0f * fabsf(avg - m);

        // e = exp(-|p|), shared by softplus and sigmoid
        const float e = __expf(-fabsf(p));
        const float softplus = __logf(1.0f + e);               // log1p(e), e in (0,1]
        const float bce = fmaxf(p, 0.0f) - p * m + softplus;

        const float r1pe = __builtin_amdgcn_rcpf(1.0f + e);    // 1/(1+e)
        const float sig = (p >= 0.0f) ? r1pe : e * r1pe;       // sigmoid(p)

        const float inter = sig * m;
        const float denom = sig + m - inter + 1.0f;            // union - inter + 1
        const float iou = 1.0f - (inter + 1.0f) * __builtin_amdgcn_rcpf(denom);

        s0 += w;
        s1 += w * (bce + iou);

        // slide window: add y+16, drop y-15
        const int ya = y + KRAD + 1;
        if (ya < H) vsum += hs[ya * W];
        const int yr = y - KRAD;
        if (yr >= 0) vsum -= hs[yr * W];
    }

    s0 = wave_reduce(s0);
    s1 = wave_reduce(s1);
    __shared__ float2 wacc[4];
    const int lane = tid & 63, wv = tid >> 6;
    if (lane == 0) wacc[wv] = make_float2(s0, s1);
    __syncthreads();
    if (tid == 0) {
        float a0 = 0.f, a1 = 0.f;
        #pragma unroll
        for (int i = 0; i < 4; ++i) { a0 += wacc[i].x; a1 += wacc[i].y; }
        partials[blockIdx.x] = make_float2(a0, a1);
    }
}

// -------- Pass 3: per-image ratio, mean over 64 images. One wave.
__global__ void finalize_kernel(const float2* __restrict__ partials,
                                float* __restrict__ out) {
    const int lane = threadIdx.x;   // 64 threads, one per image
    float s0 = 0.f, s1 = 0.f;
    #pragma unroll
    for (int j = 0; j < BLOCKS_PER_IMG; ++j) {
        const float2 pp = partials[lane * BLOCKS_PER_IMG + j];
        s0 += pp.x; s1 += pp.y;
    }
    float q = s1 / s0;
    q = wave_reduce(q);
    if (lane == 0) out[0] = q * (1.0f / (float)BATCH);
}

extern "C" void kernel_launch(void* const* d_in, const int* in_sizes, int n_in,
                              void* d_out, int out_size, void* d_ws, size_t ws_size,
                              hipStream_t stream) {
    const float* pred = (const float*)d_in[0];
    const float* mask = (const float*)d_in[1];
    float* hsum = (float*)d_ws;
    float2* partials = (float2*)((char*)d_ws + (size_t)BATCH * H * W * sizeof(float));

    hipLaunchKernelGGL(hbox_kernel, dim3(BATCH * H / 4), dim3(256), 0, stream,
                       mask, hsum);
    hipLaunchKernelGGL(loss_kernel, dim3(BATCH * BLOCKS_PER_IMG), dim3(256), 0, stream,
                       pred, mask, hsum, partials);
    hipLaunchKernelGGL(finalize_kernel, dim3(1), dim3(64), 0, stream,
                       partials, (float*)d_out);
}

// Round 3
// 44.991 us; speedup vs baseline: 3.0287x; 1.7276x over previous
//
#include <hip/hip_runtime.h>
#include <math.h>

#define BATCH 64
#define H 512
#define W 512
#define KRAD 15
#define STRIP 64               // output rows per block
#define NSTRIP (H / STRIP)     // 8 strips per image
#define RING 64                // LDS ring slots (bf16 hsum rows), &63 indexing

__device__ __forceinline__ float wave_reduce(float v) {
    #pragma unroll
    for (int off = 32; off > 0; off >>= 1) v += __shfl_xor(v, off);
    return v;
}

// f32 -> bf16 bits (round-to-nearest-even); inputs are finite non-negative sums
__device__ __forceinline__ unsigned bf16b(float f) {
    unsigned u = __float_as_uint(f);
    return (u + 0x7FFFu + ((u >> 16) & 1u)) >> 16;
}
__device__ __forceinline__ float fbf16(unsigned short s) {
    return __uint_as_float(((unsigned)s) << 16);
}

// One wave computes the 31-wide horizontal box sum of mask row r (zero padded)
// and stores it bf16-packed into ring row dst. r outside [0,H) -> zeros.
__device__ __forceinline__ void scan_row(const float* __restrict__ img_base, int r,
                                         int lane, unsigned short* dst) {
    float o[8];
    if (0 <= r && r < H) {
        const float4* in4 = reinterpret_cast<const float4*>(img_base + (size_t)r * W + lane * 8);
        float4 va = in4[0], vb = in4[1];
        float v[8] = {va.x, va.y, va.z, va.w, vb.x, vb.y, vb.z, vb.w};
        float P[8];
        float run = 0.f;
        #pragma unroll
        for (int k = 0; k < 8; ++k) { run += v[k]; P[k] = run; }
        float scan = run;
        #pragma unroll
        for (int off = 1; off < 64; off <<= 1) {
            float n = __shfl_up(scan, off);
            if (lane >= off) scan += n;
        }
        const float excl = scan - run;
        #pragma unroll
        for (int k = 0; k < 8; ++k) P[k] += excl;        // inclusive prefix at x=8*lane+k
        const float total = __shfl(P[7], 63);
        // out[x] = P[min(x+15,511)] - (x>=16 ? P[x-16] : 0)
        float shA[8], shB[8];
        shA[0] = __shfl_down(P[7], 1);
        #pragma unroll
        for (int k = 1; k < 8; ++k) shA[k] = __shfl_down(P[k - 1], 2);
        #pragma unroll
        for (int k = 0; k < 8; ++k) shB[k] = __shfl_up(P[k], 2);
        const int xb = lane * 8;
        #pragma unroll
        for (int k = 0; k < 8; ++k) {
            const int x = xb + k;
            const float A  = (x + KRAD <= W - 1) ? shA[k] : total;
            const float Bv = (x >= KRAD + 1) ? shB[k] : 0.f;
            o[k] = A - Bv;
        }
    } else {
        #pragma unroll
        for (int k = 0; k < 8; ++k) o[k] = 0.f;
    }
    uint4 wv;
    wv.x = bf16b(o[0]) | (bf16b(o[1]) << 16);
    wv.y = bf16b(o[2]) | (bf16b(o[3]) << 16);
    wv.z = bf16b(o[4]) | (bf16b(o[5]) << 16);
    wv.w = bf16b(o[6]) | (bf16b(o[7]) << 16);
    *reinterpret_cast<uint4*>(dst + lane * 8) = wv;      // 16B, conflict-free
}

// -------- Fused: horizontal scan -> bf16 LDS ring -> vertical window + loss.
__global__ __launch_bounds__(512) void fused_kernel(const float* __restrict__ pred,
                                                    const float* __restrict__ mask,
                                                    float2* __restrict__ partials) {
    __shared__ unsigned short ring[RING][W];   // 64 KB
    __shared__ float2 wacc[8];

    const int tid  = threadIdx.x;
    const int wave = tid >> 6;
    const int lane = tid & 63;
    const int img   = blockIdx.x >> 3;         // NSTRIP = 8
    const int strip = blockIdx.x & 7;
    const int r0 = strip * STRIP;
    const int c  = tid;                        // this thread's column in phase B
    const float* mk = mask + (size_t)img * H * W;
    const float* pr = pred + (size_t)img * H * W;

    // Prologue: fill ring rows r0-16 .. r0+14 (31 rows; out-of-range -> zeros)
    #pragma unroll
    for (int gp = 0; gp < 4; ++gp) {
        const int idx = gp * 8 + wave;
        if (idx < 31) {
            const int r = r0 - 16 + idx;
            scan_row(mk, r, lane, &ring[r & (RING - 1)][0]);
        }
    }
    __syncthreads();

    // Initial vertical sum: rows r0-15 .. r0+14 (30 rows)
    float vsum = 0.f;
    #pragma unroll
    for (int j = 0; j < 30; ++j) {
        vsum += fbf16(ring[(r0 - 15 + j) & (RING - 1)][c]);
    }

    float s0 = 0.f, s1 = 0.f;
    const float inv_k2 = 1.0f / 961.0f;

    for (int g = 0; g < STRIP / 8; ++g) {
        const int ybase = r0 + g * 8;
        // Phase A: each wave produces hsum row ybase+15+wave
        {
            const int r = ybase + 15 + wave;
            scan_row(mk, r, lane, &ring[r & (RING - 1)][0]);
        }
        __syncthreads();

        // Phase B: batch LDS + global reads for 8 rows, then register chain
        float addv[8], subv[8], m[8], p[8];
        #pragma unroll
        for (int i = 0; i < 8; ++i) {
            addv[i] = fbf16(ring[(ybase + i + 15) & (RING - 1)][c]);
            subv[i] = fbf16(ring[(ybase + i - 16) & (RING - 1)][c]);
        }
        #pragma unroll
        for (int i = 0; i < 8; ++i) {
            m[i] = mk[(size_t)(ybase + i) * W + c];
            p[i] = pr[(size_t)(ybase + i) * W + c];
        }
        #pragma unroll
        for (int i = 0; i < 8; ++i) {
            vsum += addv[i] - subv[i];                      // window [y-15, y+15]
            const float avg = vsum * inv_k2;
            const float w = 1.0f + 5.0f * fabsf(avg - m[i]);
            const float e = __expf(-fabsf(p[i]));
            const float softplus = __logf(1.0f + e);        // log1p(e), e in (0,1]
            const float bce = fmaxf(p[i], 0.0f) - p[i] * m[i] + softplus;
            const float r1pe = __builtin_amdgcn_rcpf(1.0f + e);
            const float sig = (p[i] >= 0.0f) ? r1pe : e * r1pe;
            const float inter = sig * m[i];
            const float denom = sig + m[i] - inter + 1.0f;  // union - inter + 1
            const float iou = 1.0f - (inter + 1.0f) * __builtin_amdgcn_rcpf(denom);
            s0 += w;
            s1 += w * (bce + iou);
        }
        __syncthreads();   // ring slots free to overwrite next group
    }

    s0 = wave_reduce(s0);
    s1 = wave_reduce(s1);
    if (lane == 0) wacc[wave] = make_float2(s0, s1);
    __syncthreads();
    if (tid == 0) {
        float a0 = 0.f, a1 = 0.f;
        #pragma unroll
        for (int i = 0; i < 8; ++i) { a0 += wacc[i].x; a1 += wacc[i].y; }
        partials[blockIdx.x] = make_float2(a0, a1);
    }
}

// -------- Finalize: per-image ratio, mean over 64 images. One wave.
__global__ void finalize_kernel(const float2* __restrict__ partials,
                                float* __restrict__ out) {
    const int lane = threadIdx.x;   // 64 threads, one per image
    float s0 = 0.f, s1 = 0.f;
    #pragma unroll
    for (int j = 0; j < NSTRIP; ++j) {
        const float2 pp = partials[lane * NSTRIP + j];
        s0 += pp.x; s1 += pp.y;
    }
    float q = s1 / s0;
    q = wave_reduce(q);
    if (lane == 0) out[0] = q * (1.0f / (float)BATCH);
}

extern "C" void kernel_launch(void* const* d_in, const int* in_sizes, int n_in,
                              void* d_out, int out_size, void* d_ws, size_t ws_size,
                              hipStream_t stream) {
    const float* pred = (const float*)d_in[0];
    const float* mask = (const float*)d_in[1];
    float2* partials = (float2*)d_ws;   // 512 * 8B

    hipLaunchKernelGGL(fused_kernel, dim3(BATCH * NSTRIP), dim3(512), 0, stream,
                       pred, mask, partials);
    hipLaunchKernelGGL(finalize_kernel, dim3(1), dim3(64), 0, stream,
                       partials, (float*)d_out);
}